// Round 13
// baseline (635.197 us; speedup 1.0000x reference)
//
#include <hip/hip_runtime.h>

#define EMB 64
#define B2SHIFT 8                 // 256 dst rows per bucket
#define B2ROWS 256
#define MAXB 1024                 // LDS hist capacity (586 buckets actual)

typedef short v8s __attribute__((ext_vector_type(8)));
typedef float v4f __attribute__((ext_vector_type(4)));

__device__ __forceinline__ float b2f(unsigned short u) {
    return __uint_as_float(((unsigned int)u) << 16);
}
__device__ __forceinline__ unsigned short f2b(float f) {
    unsigned int u = __float_as_uint(f);
    u += 0x7FFF + ((u >> 16) & 1);          // round-to-nearest-even
    return (unsigned short)(u >> 16);
}

// ---------------------------------------------------------------------------
// Bucket histogram (586 buckets): LDS pre-aggregation, ~300K global atomics
// ---------------------------------------------------------------------------
__global__ __launch_bounds__(256) void k_bhist(const int* __restrict__ dst,
                                               int* __restrict__ bins,
                                               int M, int nb2) {
    __shared__ int h[MAXB];
    for (int i = threadIdx.x; i < nb2; i += 256) h[i] = 0;
    __syncthreads();
    for (int e = blockIdx.x * 256 + threadIdx.x; e < M; e += gridDim.x * 256)
        atomicAdd(&h[dst[e] >> B2SHIFT], 1);
    __syncthreads();
    for (int i = threadIdx.x; i < nb2; i += 256)
        if (h[i]) atomicAdd(&bins[i], h[i]);
}

// ---------------------------------------------------------------------------
// Exclusive scan of nb2 (<=1024) bins -> boff[0..P], bcur copy; row_ptr[N]=M
// ---------------------------------------------------------------------------
__global__ __launch_bounds__(1024) void k_bscan(const int* __restrict__ bins,
                                                int* __restrict__ boff,
                                                int* __restrict__ bcur,
                                                int* __restrict__ row_ptr,
                                                int P, int N) {
    __shared__ int buf[1024];
    int tid = threadIdx.x;
    int v = (tid < P) ? bins[tid] : 0;
    buf[tid] = v;
    __syncthreads();
    for (int d = 1; d < 1024; d <<= 1) {
        int add = (tid >= d) ? buf[tid - d] : 0;
        __syncthreads();
        buf[tid] += add;
        __syncthreads();
    }
    if (tid < P) {
        int excl = buf[tid] - v;
        boff[tid] = excl;
        bcur[tid] = excl;
    }
    if (tid == P - 1) {
        boff[P] = buf[tid];
        row_ptr[N] = buf[tid];
    }
}

// ---------------------------------------------------------------------------
// Multisplit pass 1: block-private runs per bucket (single-writer lines)
// entry = (src << 8) | (dst & 255)
// ---------------------------------------------------------------------------
__global__ __launch_bounds__(256) void k_bin(const int* __restrict__ src,
                                             const int* __restrict__ dst,
                                             int* __restrict__ bcur,
                                             int* __restrict__ binned,
                                             int M, int nb2) {
    __shared__ int hist[MAXB];
    __shared__ int runcur[MAXB];
    int chunk = (M + gridDim.x - 1) / gridDim.x;
    int lo = blockIdx.x * chunk;
    int hi = min(lo + chunk, M);
    for (int i = threadIdx.x; i < nb2; i += 256) hist[i] = 0;
    __syncthreads();
    for (int e = lo + threadIdx.x; e < hi; e += 256)
        atomicAdd(&hist[dst[e] >> B2SHIFT], 1);
    __syncthreads();
    for (int i = threadIdx.x; i < nb2; i += 256) {
        int c = hist[i];
        runcur[i] = c ? atomicAdd(&bcur[i], c) : 0;
    }
    __syncthreads();
    for (int e = lo + threadIdx.x; e < hi; e += 256) {
        int d = dst[e];
        int pos = atomicAdd(&runcur[d >> B2SHIFT], 1);
        binned[pos] = (src[e] << B2SHIFT) | (d & (B2ROWS - 1));
    }
}

// ---------------------------------------------------------------------------
// Multisplit pass 2 + CSR finalize + embedding init (fused):
// per-bucket LDS histogram -> scan -> row_ptr & dsq -> scatter csr
// -> init egob/egow/all_eb for the bucket's 256 nodes (dsq hot in LDS)
// ---------------------------------------------------------------------------
__global__ __launch_bounds__(256) void k_csrb(
        const int* __restrict__ boff, const int* __restrict__ binned,
        int* __restrict__ row_ptr, float* __restrict__ dsq,
        int* __restrict__ csr,
        const float* __restrict__ user_emb, const float* __restrict__ item_emb,
        unsigned short* __restrict__ egob, unsigned short* __restrict__ egow,
        unsigned short* __restrict__ all_eb,
        int n_user, int N) {
    __shared__ int hist[B2ROWS];
    __shared__ int scan[B2ROWS];
    __shared__ float sdsq[B2ROWS];
    int b = blockIdx.x;
    int beg = boff[b], end = boff[b + 1];
    int tid = threadIdx.x;
    hist[tid] = 0;
    __syncthreads();
    for (int e = beg + tid; e < end; e += 256)
        atomicAdd(&hist[binned[e] & (B2ROWS - 1)], 1);
    __syncthreads();
    int c = hist[tid];
    scan[tid] = c;
    __syncthreads();
    for (int d = 1; d < B2ROWS; d <<= 1) {
        int add = (tid >= d) ? scan[tid - d] : 0;
        __syncthreads();
        scan[tid] += add;
        __syncthreads();
    }
    int excl = beg + scan[tid] - c;
    int node = (b << B2SHIFT) + tid;
    float dv = (c > 0) ? rsqrtf((float)c) : 0.0f;
    if (node < N) {
        row_ptr[node] = excl;
        dsq[node] = dv;
    }
    sdsq[tid] = dv;
    __syncthreads();
    hist[tid] = excl;               // reuse as per-node cursor
    __syncthreads();
    for (int e = beg + tid; e < end; e += 256) {
        int v = binned[e];
        int pos = atomicAdd(&hist[v & (B2ROWS - 1)], 1);
        csr[pos] = v >> B2SHIFT;
    }
    // embedding init for this bucket's nodes (coalesced)
    int node0 = b << B2SHIFT;
    int nn = min(B2ROWS, N - node0);
    for (int i = tid; i < nn * EMB; i += 256) {
        int ln = i >> 6, c2 = i & 63;
        int n2 = node0 + ln;
        float v = (n2 < n_user) ? user_emb[(size_t)n2 * EMB + c2]
                                : item_emb[(size_t)(n2 - n_user) * EMB + c2];
        unsigned short bb = f2b(v);
        egob[(size_t)n2 * EMB + c2] = bb;
        egow[(size_t)n2 * EMB + c2] = f2b(sdsq[ln] * v);
        __builtin_nontemporal_store(bb, &all_eb[(size_t)n2 * 256 + c2]);
    }
}

// ---------------------------------------------------------------------------
// side pass: one wave per node, lane = component. Indices loaded 64-at-a-time
// through lanes, extracted via readlane; 16 gathers in flight per wave.
// Epilogue emits the MFMA A-matrix: X[n][0:64]=bf16(side),
// X[n][64:128]=bf16(side*ego)
// ---------------------------------------------------------------------------
__global__ __launch_bounds__(256) void k_side(const int* __restrict__ row_ptr,
                                              const int* __restrict__ csr,
                                              const float* __restrict__ dsq,
                                              const unsigned short* __restrict__ egow,
                                              const unsigned short* __restrict__ egob,
                                              unsigned short* __restrict__ X, int N) {
    int wave = threadIdx.x >> 6;
    int lane = threadIdx.x & 63;
    int n = blockIdx.x * 4 + wave;
    if (n >= N) return;
    int beg = __builtin_amdgcn_readfirstlane(row_ptr[n]);
    int end = __builtin_amdgcn_readfirstlane(row_ptr[n + 1]);
    float a0 = 0.f, a1 = 0.f, a2 = 0.f, a3 = 0.f;
    int e = beg;
    while (e < end) {
        int take = end - e;
        if (take > 64) take = 64;
        int vidx = csr[min(e + lane, end - 1)];   // one vmem for <=64 indices
        int j = 0;
        for (; j + 16 <= take; j += 16) {
            int s[16];
#pragma unroll
            for (int u = 0; u < 16; u++)
                s[u] = __builtin_amdgcn_readlane(vidx, j + u);
            float v[16];
#pragma unroll
            for (int u = 0; u < 16; u++)
                v[u] = b2f(egow[(size_t)s[u] * EMB + lane]);
#pragma unroll
            for (int u = 0; u < 16; u += 4) {
                a0 += v[u + 0];
                a1 += v[u + 1];
                a2 += v[u + 2];
                a3 += v[u + 3];
            }
        }
        for (; j + 8 <= take; j += 8) {
            int s0 = __builtin_amdgcn_readlane(vidx, j + 0);
            int s1 = __builtin_amdgcn_readlane(vidx, j + 1);
            int s2 = __builtin_amdgcn_readlane(vidx, j + 2);
            int s3 = __builtin_amdgcn_readlane(vidx, j + 3);
            int s4 = __builtin_amdgcn_readlane(vidx, j + 4);
            int s5 = __builtin_amdgcn_readlane(vidx, j + 5);
            int s6 = __builtin_amdgcn_readlane(vidx, j + 6);
            int s7 = __builtin_amdgcn_readlane(vidx, j + 7);
            float v0 = b2f(egow[(size_t)s0 * EMB + lane]);
            float v1 = b2f(egow[(size_t)s1 * EMB + lane]);
            float v2 = b2f(egow[(size_t)s2 * EMB + lane]);
            float v3 = b2f(egow[(size_t)s3 * EMB + lane]);
            float v4 = b2f(egow[(size_t)s4 * EMB + lane]);
            float v5 = b2f(egow[(size_t)s5 * EMB + lane]);
            float v6 = b2f(egow[(size_t)s6 * EMB + lane]);
            float v7 = b2f(egow[(size_t)s7 * EMB + lane]);
            a0 += v0 + v4;
            a1 += v1 + v5;
            a2 += v2 + v6;
            a3 += v3 + v7;
        }
        for (; j < take; j++) {
            int s = __builtin_amdgcn_readlane(vidx, j);
            a0 += b2f(egow[(size_t)s * EMB + lane]);
        }
        e += take;
    }
    float s = dsq[n] * ((a0 + a1) + (a2 + a3));
    float eg = b2f(egob[(size_t)n * EMB + lane]);
    X[(size_t)n * 128 + lane] = f2b(s);
    X[(size_t)n * 128 + 64 + lane] = f2b(s * eg);
}

// ---------------------------------------------------------------------------
// MFMA transform: C = X @ [Wgc; Wbi] + b  (K=128, bf16 16x16x32)
// W^T staged in LDS as bf16 (stride 136 shorts). 16 B-fragments in regs;
// 4 row-tiles/wave. Epilogue: leaky-relu, quad-shfl row-norm, bf16 stores;
// all_eb stores non-temporal (write-once, read-once at the end).
// ---------------------------------------------------------------------------
__global__ __launch_bounds__(256, 2) void k_mt(
        const unsigned short* __restrict__ X,
        unsigned short* __restrict__ egob, unsigned short* __restrict__ egow,
        const float* __restrict__ dsq,
        const float* __restrict__ Wgc, const float* __restrict__ bgc,
        const float* __restrict__ Wbi, const float* __restrict__ bbi,
        unsigned short* __restrict__ all_eb, int N, int layer_col) {
    __shared__ unsigned short sWT[64 * 136];   // [n][k] bf16, k in [0,128)
    __shared__ float sB[64];
    int tid = threadIdx.x;
    for (int i = tid; i < 64 * 64; i += 256) {
        int k = i >> 6, n = i & 63;
        sWT[n * 136 + k]      = f2b(Wgc[i]);
        sWT[n * 136 + 64 + k] = f2b(Wbi[i]);
    }
    if (tid < 64) sB[tid] = bgc[tid] + bbi[tid];
    __syncthreads();

    int wave = tid >> 6, lane = tid & 63;
    int q = lane >> 4, col = lane & 15;

    v8s Bf[4][4];                               // [nt][kt]
#pragma unroll
    for (int nt = 0; nt < 4; nt++)
#pragma unroll
        for (int kt = 0; kt < 4; kt++)
            Bf[nt][kt] = *(const v8s*)&sWT[(nt * 16 + col) * 136 + kt * 32 + q * 8];

    int nrt = (N + 15) >> 4;
    int rt0 = (blockIdx.x * 4 + wave) * 4;      // 4 row-tiles per wave
    int rt1 = min(rt0 + 4, nrt);
    for (int t = rt0; t < rt1; t++) {
        int r0 = t << 4;
        int rowA = min(r0 + col, N - 1);
        v8s Af[4];
#pragma unroll
        for (int kt = 0; kt < 4; kt++)
            Af[kt] = *(const v8s*)&X[(size_t)rowA * 128 + kt * 32 + q * 8];
        v4f acc[4];
#pragma unroll
        for (int nt = 0; nt < 4; nt++) {
            float b = sB[nt * 16 + col];
            acc[nt] = (v4f){b, b, b, b};
        }
#pragma unroll
        for (int kt = 0; kt < 4; kt++)
#pragma unroll
            for (int nt = 0; nt < 4; nt++)
                acc[nt] = __builtin_amdgcn_mfma_f32_16x16x32_bf16(
                    Af[kt], Bf[nt][kt], acc[nt], 0, 0, 0);
        // epilogue: row = r0 + q*4 + reg, col = nt*16 + (lane&15)
#pragma unroll
        for (int reg = 0; reg < 4; reg++) {
            int row = r0 + q * 4 + reg;
            float v[4];
            float ssq = 0.f;
#pragma unroll
            for (int nt = 0; nt < 4; nt++) {
                float x = acc[nt][reg];
                x = x > 0.f ? x : 0.2f * x;
                v[nt] = x;
                ssq += x * x;
            }
            ssq += __shfl_xor(ssq, 1, 64);
            ssq += __shfl_xor(ssq, 2, 64);
            ssq += __shfl_xor(ssq, 4, 64);
            ssq += __shfl_xor(ssq, 8, 64);
            float inv = 1.0f / fmaxf(sqrtf(ssq), 1e-12f);
            if (row < N) {
                float dn = dsq[row];
#pragma unroll
                for (int nt = 0; nt < 4; nt++) {
                    int c = nt * 16 + col;
                    egob[(size_t)row * EMB + c] = f2b(v[nt]);
                    egow[(size_t)row * EMB + c] = f2b(v[nt] * dn);
                    __builtin_nontemporal_store(
                        f2b(v[nt] * inv),
                        &all_eb[(size_t)row * 256 + layer_col + c]);
                }
            }
        }
    }
}

// ---------------------------------------------------------------------------
// out(f32) = [all_eb[users], all_eb[nu+pos], all_eb[nu+neg]] (bf16 -> f32)
// ---------------------------------------------------------------------------
__global__ void k_gather(const unsigned short* __restrict__ all_eb,
                         const int* __restrict__ users,
                         const int* __restrict__ pos,
                         const int* __restrict__ neg,
                         float* __restrict__ out, int n_user, int batch) {
    int idx = blockIdx.x * blockDim.x + threadIdx.x;
    int total = batch * 256;
    if (idx >= 3 * total) return;
    int which = idx / total;
    int r = idx - which * total;
    int b = r >> 8;
    int c = r & 255;
    int node;
    if (which == 0) node = users[b];
    else if (which == 1) node = n_user + pos[b];
    else node = n_user + neg[b];
    out[idx] = b2f(all_eb[(size_t)node * 256 + c]);
}

static inline size_t align256(size_t x) { return (x + 255) & ~(size_t)255; }

extern "C" void kernel_launch(void* const* d_in, const int* in_sizes, int n_in,
                              void* d_out, int out_size, void* d_ws, size_t ws_size,
                              hipStream_t stream) {
    const float* user_emb = (const float*)d_in[0];
    const float* item_emb = (const float*)d_in[1];
    const float* W_gc = (const float*)d_in[2];
    const float* b_gc = (const float*)d_in[3];
    const float* W_bi = (const float*)d_in[4];
    const float* b_bi = (const float*)d_in[5];
    const int* edge_src = (const int*)d_in[7];
    const int* edge_dst = (const int*)d_in[8];
    const int* users = (const int*)d_in[9];
    const int* pos = (const int*)d_in[10];
    const int* neg = (const int*)d_in[11];

    int n_user = in_sizes[0] / EMB;
    int n_item = in_sizes[1] / EMB;
    int N = n_user + n_item;
    int M = in_sizes[6];
    int layers = in_sizes[2] / (EMB * EMB);
    int batch = in_sizes[9];
    float* out = (float*)d_out;

    int nb2 = (N + B2ROWS - 1) >> B2SHIFT;       // 586 buckets
    int nrt = (N + 15) >> 4;                     // 16-row tiles

    // workspace carve (~187 MB)
    char* p = (char*)d_ws;
    unsigned short* egob = (unsigned short*)p;   p += align256((size_t)N * EMB * 2);
    unsigned short* egow = (unsigned short*)p;   p += align256((size_t)N * EMB * 2);
    unsigned short* X = (unsigned short*)p;      p += align256((size_t)N * 128 * 2);
    unsigned short* all_eb = (unsigned short*)p; p += align256((size_t)N * 256 * 2);
    float* dsq = (float*)p;            p += align256((size_t)N * 4);
    int* row_ptr = (int*)p;            p += align256((size_t)(N + 1) * 4);
    int* bins = (int*)p;               p += align256((size_t)nb2 * 4);
    int* boff = (int*)p;               p += align256((size_t)(nb2 + 1) * 4);
    int* bcur = (int*)p;               p += align256((size_t)nb2 * 4);
    int* binned = (int*)p;             p += align256((size_t)M * 4);
    int* csr = (int*)p;                p += align256((size_t)M * 4);

    hipMemsetAsync(bins, 0, (size_t)nb2 * 4, stream);   // 2.3 KB

    // bucket-first CSR build (produces row_ptr, dsq, csr, and init'd embs)
    k_bhist<<<512, 256, 0, stream>>>(edge_dst, bins, M, nb2);
    k_bscan<<<1, 1024, 0, stream>>>(bins, boff, bcur, row_ptr, nb2, N);
    k_bin<<<512, 256, 0, stream>>>(edge_src, edge_dst, bcur, binned, M, nb2);
    k_csrb<<<nb2, 256, 0, stream>>>(boff, binned, row_ptr, dsq, csr,
                                    user_emb, item_emb, egob, egow, all_eb,
                                    n_user, N);

    for (int k = 0; k < layers; k++) {
        k_side<<<(N + 3) / 4, 256, 0, stream>>>(row_ptr, csr, dsq, egow, egob, X, N);
        k_mt<<<(nrt + 15) / 16, 256, 0, stream>>>(
            X, egob, egow, dsq,
            W_gc + (size_t)k * EMB * EMB, b_gc + (size_t)k * EMB,
            W_bi + (size_t)k * EMB * EMB, b_bi + (size_t)k * EMB,
            all_eb, N, (k + 1) * EMB);
    }

    k_gather<<<(3 * batch * 256 + 255) / 256, 256, 0, stream>>>(
        all_eb, users, pos, neg, out, n_user, batch);
}

// Round 14
// 605.934 us; speedup vs baseline: 1.0483x; 1.0483x over previous
//
#include <hip/hip_runtime.h>

#define EMB 64
#define B2SHIFT 8                 // 256 dst rows per bucket
#define B2ROWS 256
#define MAXB 1024                 // LDS hist capacity (586 buckets actual)

typedef short v8s __attribute__((ext_vector_type(8)));
typedef float v4f __attribute__((ext_vector_type(4)));

__device__ __forceinline__ float b2f(unsigned short u) {
    return __uint_as_float(((unsigned int)u) << 16);
}
__device__ __forceinline__ unsigned short f2b(float f) {
    unsigned int u = __float_as_uint(f);
    u += 0x7FFF + ((u >> 16) & 1);          // round-to-nearest-even
    return (unsigned short)(u >> 16);
}

// ---------------------------------------------------------------------------
// init (runs AFTER csr build so dsq is available), full-grid for parallelism:
// egob = bf16(ego); egow = bf16(dsq[n]*ego); all_eb[:,0:64] = bf16(ego) (NT)
// ---------------------------------------------------------------------------
__global__ void k_init_ego(const float* __restrict__ user_emb,
                           const float* __restrict__ item_emb,
                           const float* __restrict__ dsq,
                           unsigned short* __restrict__ egob,
                           unsigned short* __restrict__ egow,
                           unsigned short* __restrict__ all_eb,
                           int n_user, int N) {
    int idx = blockIdx.x * blockDim.x + threadIdx.x;
    int total = N * EMB;
    if (idx >= total) return;
    int n = idx >> 6;
    int c = idx & 63;
    float v = (n < n_user) ? user_emb[idx] : item_emb[(size_t)(n - n_user) * EMB + c];
    unsigned short b = f2b(v);
    egob[idx] = b;
    egow[idx] = f2b(dsq[n] * v);
    __builtin_nontemporal_store(b, &all_eb[(size_t)n * 256 + c]);
}

// ---------------------------------------------------------------------------
// Bucket histogram (586 buckets): LDS pre-aggregation, ~300K global atomics
// ---------------------------------------------------------------------------
__global__ __launch_bounds__(256) void k_bhist(const int* __restrict__ dst,
                                               int* __restrict__ bins,
                                               int M, int nb2) {
    __shared__ int h[MAXB];
    for (int i = threadIdx.x; i < nb2; i += 256) h[i] = 0;
    __syncthreads();
    for (int e = blockIdx.x * 256 + threadIdx.x; e < M; e += gridDim.x * 256)
        atomicAdd(&h[dst[e] >> B2SHIFT], 1);
    __syncthreads();
    for (int i = threadIdx.x; i < nb2; i += 256)
        if (h[i]) atomicAdd(&bins[i], h[i]);
}

// ---------------------------------------------------------------------------
// Exclusive scan of nb2 (<=1024) bins -> boff[0..P], bcur copy; row_ptr[N]=M
// ---------------------------------------------------------------------------
__global__ __launch_bounds__(1024) void k_bscan(const int* __restrict__ bins,
                                                int* __restrict__ boff,
                                                int* __restrict__ bcur,
                                                int* __restrict__ row_ptr,
                                                int P, int N) {
    __shared__ int buf[1024];
    int tid = threadIdx.x;
    int v = (tid < P) ? bins[tid] : 0;
    buf[tid] = v;
    __syncthreads();
    for (int d = 1; d < 1024; d <<= 1) {
        int add = (tid >= d) ? buf[tid - d] : 0;
        __syncthreads();
        buf[tid] += add;
        __syncthreads();
    }
    if (tid < P) {
        int excl = buf[tid] - v;
        boff[tid] = excl;
        bcur[tid] = excl;
    }
    if (tid == P - 1) {
        boff[P] = buf[tid];
        row_ptr[N] = buf[tid];
    }
}

// ---------------------------------------------------------------------------
// Multisplit pass 1: block-private runs per bucket (single-writer lines)
// entry = (src << 8) | (dst & 255)
// ---------------------------------------------------------------------------
__global__ __launch_bounds__(256) void k_bin(const int* __restrict__ src,
                                             const int* __restrict__ dst,
                                             int* __restrict__ bcur,
                                             int* __restrict__ binned,
                                             int M, int nb2) {
    __shared__ int hist[MAXB];
    __shared__ int runcur[MAXB];
    int chunk = (M + gridDim.x - 1) / gridDim.x;
    int lo = blockIdx.x * chunk;
    int hi = min(lo + chunk, M);
    for (int i = threadIdx.x; i < nb2; i += 256) hist[i] = 0;
    __syncthreads();
    for (int e = lo + threadIdx.x; e < hi; e += 256)
        atomicAdd(&hist[dst[e] >> B2SHIFT], 1);
    __syncthreads();
    for (int i = threadIdx.x; i < nb2; i += 256) {
        int c = hist[i];
        runcur[i] = c ? atomicAdd(&bcur[i], c) : 0;
    }
    __syncthreads();
    for (int e = lo + threadIdx.x; e < hi; e += 256) {
        int d = dst[e];
        int pos = atomicAdd(&runcur[d >> B2SHIFT], 1);
        binned[pos] = (src[e] << B2SHIFT) | (d & (B2ROWS - 1));
    }
}

// ---------------------------------------------------------------------------
// Multisplit pass 2 + CSR finalize (lean): per-bucket LDS histogram -> scan
// -> row_ptr & dsq -> scatter csr inside the bucket's L2-local window
// ---------------------------------------------------------------------------
__global__ __launch_bounds__(256) void k_csrb(const int* __restrict__ boff,
                                              const int* __restrict__ binned,
                                              int* __restrict__ row_ptr,
                                              float* __restrict__ dsq,
                                              int* __restrict__ csr, int N) {
    __shared__ int hist[B2ROWS];
    __shared__ int scan[B2ROWS];
    int b = blockIdx.x;
    int beg = boff[b], end = boff[b + 1];
    int tid = threadIdx.x;
    hist[tid] = 0;
    __syncthreads();
    for (int e = beg + tid; e < end; e += 256)
        atomicAdd(&hist[binned[e] & (B2ROWS - 1)], 1);
    __syncthreads();
    int c = hist[tid];
    scan[tid] = c;
    __syncthreads();
    for (int d = 1; d < B2ROWS; d <<= 1) {
        int add = (tid >= d) ? scan[tid - d] : 0;
        __syncthreads();
        scan[tid] += add;
        __syncthreads();
    }
    int excl = beg + scan[tid] - c;
    int node = (b << B2SHIFT) + tid;
    if (node < N) {
        row_ptr[node] = excl;
        dsq[node] = (c > 0) ? rsqrtf((float)c) : 0.0f;
    }
    __syncthreads();
    hist[tid] = excl;               // reuse as per-node cursor
    __syncthreads();
    for (int e = beg + tid; e < end; e += 256) {
        int v = binned[e];
        int pos = atomicAdd(&hist[v & (B2ROWS - 1)], 1);
        csr[pos] = v >> B2SHIFT;
    }
}

// ---------------------------------------------------------------------------
// side pass: one wave per node, lane = component. Indices loaded 64-at-a-time
// through lanes, extracted via readlane; 16 gathers in flight per wave.
// Epilogue emits the MFMA A-matrix: X[n][0:64]=bf16(side),
// X[n][64:128]=bf16(side*ego)
// ---------------------------------------------------------------------------
__global__ __launch_bounds__(256) void k_side(const int* __restrict__ row_ptr,
                                              const int* __restrict__ csr,
                                              const float* __restrict__ dsq,
                                              const unsigned short* __restrict__ egow,
                                              const unsigned short* __restrict__ egob,
                                              unsigned short* __restrict__ X, int N) {
    int wave = threadIdx.x >> 6;
    int lane = threadIdx.x & 63;
    int n = blockIdx.x * 4 + wave;
    if (n >= N) return;
    int beg = __builtin_amdgcn_readfirstlane(row_ptr[n]);
    int end = __builtin_amdgcn_readfirstlane(row_ptr[n + 1]);
    float a0 = 0.f, a1 = 0.f, a2 = 0.f, a3 = 0.f;
    int e = beg;
    while (e < end) {
        int take = end - e;
        if (take > 64) take = 64;
        int vidx = csr[min(e + lane, end - 1)];   // one vmem for <=64 indices
        int j = 0;
        for (; j + 16 <= take; j += 16) {
            int s[16];
#pragma unroll
            for (int u = 0; u < 16; u++)
                s[u] = __builtin_amdgcn_readlane(vidx, j + u);
            float v[16];
#pragma unroll
            for (int u = 0; u < 16; u++)
                v[u] = b2f(egow[(size_t)s[u] * EMB + lane]);
#pragma unroll
            for (int u = 0; u < 16; u += 4) {
                a0 += v[u + 0];
                a1 += v[u + 1];
                a2 += v[u + 2];
                a3 += v[u + 3];
            }
        }
        for (; j + 8 <= take; j += 8) {
            int s0 = __builtin_amdgcn_readlane(vidx, j + 0);
            int s1 = __builtin_amdgcn_readlane(vidx, j + 1);
            int s2 = __builtin_amdgcn_readlane(vidx, j + 2);
            int s3 = __builtin_amdgcn_readlane(vidx, j + 3);
            int s4 = __builtin_amdgcn_readlane(vidx, j + 4);
            int s5 = __builtin_amdgcn_readlane(vidx, j + 5);
            int s6 = __builtin_amdgcn_readlane(vidx, j + 6);
            int s7 = __builtin_amdgcn_readlane(vidx, j + 7);
            float v0 = b2f(egow[(size_t)s0 * EMB + lane]);
            float v1 = b2f(egow[(size_t)s1 * EMB + lane]);
            float v2 = b2f(egow[(size_t)s2 * EMB + lane]);
            float v3 = b2f(egow[(size_t)s3 * EMB + lane]);
            float v4 = b2f(egow[(size_t)s4 * EMB + lane]);
            float v5 = b2f(egow[(size_t)s5 * EMB + lane]);
            float v6 = b2f(egow[(size_t)s6 * EMB + lane]);
            float v7 = b2f(egow[(size_t)s7 * EMB + lane]);
            a0 += v0 + v4;
            a1 += v1 + v5;
            a2 += v2 + v6;
            a3 += v3 + v7;
        }
        for (; j < take; j++) {
            int s = __builtin_amdgcn_readlane(vidx, j);
            a0 += b2f(egow[(size_t)s * EMB + lane]);
        }
        e += take;
    }
    float s = dsq[n] * ((a0 + a1) + (a2 + a3));
    float eg = b2f(egob[(size_t)n * EMB + lane]);
    X[(size_t)n * 128 + lane] = f2b(s);
    X[(size_t)n * 128 + 64 + lane] = f2b(s * eg);
}

// ---------------------------------------------------------------------------
// MFMA transform: C = X @ [Wgc; Wbi] + b  (K=128, bf16 16x16x32)
// W^T staged in LDS as bf16 (stride 136 shorts). 16 B-fragments in regs;
// 4 row-tiles/wave. Epilogue: leaky-relu, quad-shfl row-norm, bf16 stores;
// all_eb stores non-temporal (write-once, read-once at the end).
// ---------------------------------------------------------------------------
__global__ __launch_bounds__(256, 2) void k_mt(
        const unsigned short* __restrict__ X,
        unsigned short* __restrict__ egob, unsigned short* __restrict__ egow,
        const float* __restrict__ dsq,
        const float* __restrict__ Wgc, const float* __restrict__ bgc,
        const float* __restrict__ Wbi, const float* __restrict__ bbi,
        unsigned short* __restrict__ all_eb, int N, int layer_col) {
    __shared__ unsigned short sWT[64 * 136];   // [n][k] bf16, k in [0,128)
    __shared__ float sB[64];
    int tid = threadIdx.x;
    for (int i = tid; i < 64 * 64; i += 256) {
        int k = i >> 6, n = i & 63;
        sWT[n * 136 + k]      = f2b(Wgc[i]);
        sWT[n * 136 + 64 + k] = f2b(Wbi[i]);
    }
    if (tid < 64) sB[tid] = bgc[tid] + bbi[tid];
    __syncthreads();

    int wave = tid >> 6, lane = tid & 63;
    int q = lane >> 4, col = lane & 15;

    v8s Bf[4][4];                               // [nt][kt]
#pragma unroll
    for (int nt = 0; nt < 4; nt++)
#pragma unroll
        for (int kt = 0; kt < 4; kt++)
            Bf[nt][kt] = *(const v8s*)&sWT[(nt * 16 + col) * 136 + kt * 32 + q * 8];

    int nrt = (N + 15) >> 4;
    int rt0 = (blockIdx.x * 4 + wave) * 4;      // 4 row-tiles per wave
    int rt1 = min(rt0 + 4, nrt);
    for (int t = rt0; t < rt1; t++) {
        int r0 = t << 4;
        int rowA = min(r0 + col, N - 1);
        v8s Af[4];
#pragma unroll
        for (int kt = 0; kt < 4; kt++)
            Af[kt] = *(const v8s*)&X[(size_t)rowA * 128 + kt * 32 + q * 8];
        v4f acc[4];
#pragma unroll
        for (int nt = 0; nt < 4; nt++) {
            float b = sB[nt * 16 + col];
            acc[nt] = (v4f){b, b, b, b};
        }
#pragma unroll
        for (int kt = 0; kt < 4; kt++)
#pragma unroll
            for (int nt = 0; nt < 4; nt++)
                acc[nt] = __builtin_amdgcn_mfma_f32_16x16x32_bf16(
                    Af[kt], Bf[nt][kt], acc[nt], 0, 0, 0);
        // epilogue: row = r0 + q*4 + reg, col = nt*16 + (lane&15)
#pragma unroll
        for (int reg = 0; reg < 4; reg++) {
            int row = r0 + q * 4 + reg;
            float v[4];
            float ssq = 0.f;
#pragma unroll
            for (int nt = 0; nt < 4; nt++) {
                float x = acc[nt][reg];
                x = x > 0.f ? x : 0.2f * x;
                v[nt] = x;
                ssq += x * x;
            }
            ssq += __shfl_xor(ssq, 1, 64);
            ssq += __shfl_xor(ssq, 2, 64);
            ssq += __shfl_xor(ssq, 4, 64);
            ssq += __shfl_xor(ssq, 8, 64);
            float inv = 1.0f / fmaxf(sqrtf(ssq), 1e-12f);
            if (row < N) {
                float dn = dsq[row];
#pragma unroll
                for (int nt = 0; nt < 4; nt++) {
                    int c = nt * 16 + col;
                    egob[(size_t)row * EMB + c] = f2b(v[nt]);
                    egow[(size_t)row * EMB + c] = f2b(v[nt] * dn);
                    __builtin_nontemporal_store(
                        f2b(v[nt] * inv),
                        &all_eb[(size_t)row * 256 + layer_col + c]);
                }
            }
        }
    }
}

// ---------------------------------------------------------------------------
// out(f32) = [all_eb[users], all_eb[nu+pos], all_eb[nu+neg]] (bf16 -> f32)
// ---------------------------------------------------------------------------
__global__ void k_gather(const unsigned short* __restrict__ all_eb,
                         const int* __restrict__ users,
                         const int* __restrict__ pos,
                         const int* __restrict__ neg,
                         float* __restrict__ out, int n_user, int batch) {
    int idx = blockIdx.x * blockDim.x + threadIdx.x;
    int total = batch * 256;
    if (idx >= 3 * total) return;
    int which = idx / total;
    int r = idx - which * total;
    int b = r >> 8;
    int c = r & 255;
    int node;
    if (which == 0) node = users[b];
    else if (which == 1) node = n_user + pos[b];
    else node = n_user + neg[b];
    out[idx] = b2f(all_eb[(size_t)node * 256 + c]);
}

static inline size_t align256(size_t x) { return (x + 255) & ~(size_t)255; }

extern "C" void kernel_launch(void* const* d_in, const int* in_sizes, int n_in,
                              void* d_out, int out_size, void* d_ws, size_t ws_size,
                              hipStream_t stream) {
    const float* user_emb = (const float*)d_in[0];
    const float* item_emb = (const float*)d_in[1];
    const float* W_gc = (const float*)d_in[2];
    const float* b_gc = (const float*)d_in[3];
    const float* W_bi = (const float*)d_in[4];
    const float* b_bi = (const float*)d_in[5];
    const int* edge_src = (const int*)d_in[7];
    const int* edge_dst = (const int*)d_in[8];
    const int* users = (const int*)d_in[9];
    const int* pos = (const int*)d_in[10];
    const int* neg = (const int*)d_in[11];

    int n_user = in_sizes[0] / EMB;
    int n_item = in_sizes[1] / EMB;
    int N = n_user + n_item;
    int M = in_sizes[6];
    int layers = in_sizes[2] / (EMB * EMB);
    int batch = in_sizes[9];
    float* out = (float*)d_out;

    int nb2 = (N + B2ROWS - 1) >> B2SHIFT;       // 586 buckets
    int nrt = (N + 15) >> 4;                     // 16-row tiles

    // workspace carve (~187 MB)
    char* p = (char*)d_ws;
    unsigned short* egob = (unsigned short*)p;   p += align256((size_t)N * EMB * 2);
    unsigned short* egow = (unsigned short*)p;   p += align256((size_t)N * EMB * 2);
    unsigned short* X = (unsigned short*)p;      p += align256((size_t)N * 128 * 2);
    unsigned short* all_eb = (unsigned short*)p; p += align256((size_t)N * 256 * 2);
    float* dsq = (float*)p;            p += align256((size_t)N * 4);
    int* row_ptr = (int*)p;            p += align256((size_t)(N + 1) * 4);
    int* bins = (int*)p;               p += align256((size_t)nb2 * 4);
    int* boff = (int*)p;               p += align256((size_t)(nb2 + 1) * 4);
    int* bcur = (int*)p;               p += align256((size_t)nb2 * 4);
    int* binned = (int*)p;             p += align256((size_t)M * 4);
    int* csr = (int*)p;                p += align256((size_t)M * 4);

    hipMemsetAsync(bins, 0, (size_t)nb2 * 4, stream);   // 2.3 KB

    // bucket-first CSR build (produces row_ptr, dsq, csr)
    k_bhist<<<512, 256, 0, stream>>>(edge_dst, bins, M, nb2);
    k_bscan<<<1, 1024, 0, stream>>>(bins, boff, bcur, row_ptr, nb2, N);
    k_bin<<<512, 256, 0, stream>>>(edge_src, edge_dst, bcur, binned, M, nb2);
    k_csrb<<<nb2, 256, 0, stream>>>(boff, binned, row_ptr, dsq, csr, N);

    // init AFTER csrb (needs dsq for the pre-scaled gather table)
    k_init_ego<<<(N * EMB + 255) / 256, 256, 0, stream>>>(
        user_emb, item_emb, dsq, egob, egow, all_eb, n_user, N);

    for (int k = 0; k < layers; k++) {
        k_side<<<(N + 3) / 4, 256, 0, stream>>>(row_ptr, csr, dsq, egow, egob, X, N);
        k_mt<<<(nrt + 15) / 16, 256, 0, stream>>>(
            X, egob, egow, dsq,
            W_gc + (size_t)k * EMB * EMB, b_gc + (size_t)k * EMB,
            W_bi + (size_t)k * EMB * EMB, b_bi + (size_t)k * EMB,
            all_eb, N, (k + 1) * EMB);
    }

    k_gather<<<(3 * batch * 256 + 255) / 256, 256, 0, stream>>>(
        all_eb, users, pos, neg, out, n_user, batch);
}